// Round 1
// baseline (4369.510 us; speedup 1.0000x reference)
//
#include <hip/hip_runtime.h>

// RVQ fused kernel, f32.
// x: [16,4096,256] f32 -> N=65536 rows, D=256
// emb: [8,1024,256] f32
// out: [quantized 16777216][loss 1][indices-as-float 524288]
// ws:  [e2 8192 f32][lossPart 1024 f32]

#define NROWS   65536
#define DDIM    256
#define KCODES  1024
#define QSTAGES 8
#define BR      64     // rows per block
#define RS      68     // res LDS row stride (pad vs 64 to break transpose conflicts)
#define BK      64     // codes per k-tile
#define ES      68     // et LDS row stride
#define BD      32     // d-chunk staged per step

__global__ void e2_kernel(const float* __restrict__ emb, float* __restrict__ e2) {
  const int row  = blockIdx.x * 4 + (threadIdx.x >> 6);
  const int lane = threadIdx.x & 63;
  const float4 v = ((const float4*)(emb + (size_t)row * DDIM))[lane];
  float s = v.x * v.x + v.y * v.y + v.z * v.z + v.w * v.w;
  #pragma unroll
  for (int m = 32; m >= 1; m >>= 1) s += __shfl_xor(s, m);
  if (lane == 0) e2[row] = s;
}

__global__ __launch_bounds__(256, 2)
void rvq_kernel(const float* __restrict__ x, const float* __restrict__ emb,
                const float* __restrict__ e2g, float* __restrict__ out,
                float* __restrict__ outIdx, float* __restrict__ lossPart)
{
  __shared__ __align__(16) float res[DDIM][RS];  // 69.6 KB residual, [d][row]
  __shared__ __align__(16) float et[BD][ES];     // 8.7 KB code tile, [d][code]
  __shared__ int   sidx[BR];
  __shared__ float red[4];

  const int tid = threadIdx.x;
  const int tx = tid & 15, ty = tid >> 4;        // 16x16 thread grid -> 64x64 tile
  const size_t rowBase = (size_t)blockIdx.x * BR;

  // ---- load x tile -> res (transposed [d][row]) ----
  #pragma unroll
  for (int it = 0; it < 16; ++it) {
    const int d4 = (tid & 15) + 16 * (it & 3);
    const int r  = (tid >> 4) + 16 * (it >> 2);
    const float4 v = ((const float4*)(x + (rowBase + r) * DDIM))[d4];
    res[4 * d4 + 0][r] = v.x; res[4 * d4 + 1][r] = v.y;
    res[4 * d4 + 2][r] = v.z; res[4 * d4 + 3][r] = v.w;
  }

  float lossAcc = 0.f;
  const int sc  = tid >> 3;  // staging: code offset 0..31 (contiguous 32B/lane-group reads)
  const int sd4 = tid & 7;   // staging: f4 index within 32-d chunk

  for (int qi = 0; qi < QSTAGES; ++qi) {
    const float* embq = emb + (size_t)qi * (KCODES * DDIM);
    const float* e2q  = e2g + qi * KCODES;

    float bestV[4]; int bestI[4];
    #pragma unroll
    for (int i = 0; i < 4; ++i) { bestV[i] = 3.4e38f; bestI[i] = 0; }

    // prefetch pipeline registers (step 0 = kt 0, ch 0)
    float4 na = {0, 0, 0, 0}, nb = {0, 0, 0, 0};
    float4 pa = ((const float4*)(embq + (size_t)sc * DDIM))[sd4];
    float4 pb = ((const float4*)(embq + (size_t)(32 + sc) * DDIM))[sd4];

    for (int kt = 0; kt < KCODES / BK; ++kt) {
      float acc[4][4];
      #pragma unroll
      for (int i = 0; i < 4; ++i)
        #pragma unroll
        for (int j = 0; j < 4; ++j) acc[i][j] = 0.f;

      for (int ch = 0; ch < DDIM / BD; ++ch) {
        __syncthreads();                       // prior compute done reading et
        et[4 * sd4 + 0][sc] = pa.x; et[4 * sd4 + 1][sc] = pa.y;
        et[4 * sd4 + 2][sc] = pa.z; et[4 * sd4 + 3][sc] = pa.w;
        et[4 * sd4 + 0][32 + sc] = pb.x; et[4 * sd4 + 1][32 + sc] = pb.y;
        et[4 * sd4 + 2][32 + sc] = pb.z; et[4 * sd4 + 3][32 + sc] = pb.w;
        const int s = kt * 8 + ch + 1;         // issue next chunk's loads early
        if (s < 128) {
          const float* bp = embq + (size_t)((s >> 3) * BK) * DDIM + (s & 7) * BD;
          na = ((const float4*)(bp + (size_t)sc * DDIM))[sd4];
          nb = ((const float4*)(bp + (size_t)(32 + sc) * DDIM))[sd4];
        }
        __syncthreads();                       // et ready
        #pragma unroll
        for (int d = 0; d < BD; ++d) {
          const float4 rv4 = *(const float4*)&res[ch * BD + d][4 * ty];
          const float4 ev4 = *(const float4*)&et[d][4 * tx];
          const float rv[4] = {rv4.x, rv4.y, rv4.z, rv4.w};
          const float ev[4] = {ev4.x, ev4.y, ev4.z, ev4.w};
          #pragma unroll
          for (int i = 0; i < 4; ++i)
            #pragma unroll
            for (int j = 0; j < 4; ++j)
              acc[i][j] += rv[i] * ev[j];
        }
        pa = na; pb = nb;
      }

      // score = ||e||^2 - 2 r.e ; fold into running per-row argmin
      const int colBase = kt * BK + 4 * tx;
      const float4 e4 = *(const float4*)(e2q + colBase);
      const float e2v[4] = {e4.x, e4.y, e4.z, e4.w};
      #pragma unroll
      for (int i = 0; i < 4; ++i) {
        float v = e2v[0] - 2.f * acc[i][0];
        int ix = colBase;
        #pragma unroll
        for (int j = 1; j < 4; ++j) {
          const float vj = e2v[j] - 2.f * acc[i][j];
          if (vj < v) { v = vj; ix = colBase + j; }   // ascending j: ties keep lower idx
        }
        #pragma unroll
        for (int m = 1; m <= 8; m <<= 1) {            // 16-lane lexicographic min
          const float ov = __shfl_xor(v, m);
          const int   oi = __shfl_xor(ix, m);
          if (ov < v || (ov == v && oi < ix)) { v = ov; ix = oi; }
        }
        if (v < bestV[i]) { bestV[i] = v; bestI[i] = ix; }  // earlier tile wins ties
      }
    }

    if (tx == 0) {
      #pragma unroll
      for (int i = 0; i < 4; ++i) sidx[4 * ty + i] = bestI[i];
    }
    __syncthreads();

    // ---- residual update + loss (4 threads per row, 64 d each) ----
    {
      const int r = tid >> 2, qq = tid & 3;
      const int code = sidx[r];
      const float4* eg = (const float4*)(embq + (size_t)code * DDIM + qq * 64);
      float ls = 0.f;
      #pragma unroll
      for (int f = 0; f < 16; ++f) {
        const float4 ev = eg[f];
        const int d0 = qq * 64 + 4 * f;
        float a;
        a = res[d0 + 0][r] - ev.x; res[d0 + 0][r] = a; ls += a * a;
        a = res[d0 + 1][r] - ev.y; res[d0 + 1][r] = a; ls += a * a;
        a = res[d0 + 2][r] - ev.z; res[d0 + 2][r] = a; ls += a * a;
        a = res[d0 + 3][r] - ev.w; res[d0 + 3][r] = a; ls += a * a;
      }
      lossAcc += ls;
    }
    if (tid < BR) outIdx[(rowBase + tid) * QSTAGES + qi] = (float)sidx[tid];
    __syncthreads();
  }

  // ---- quantized output: out = x - res_final ----
  #pragma unroll
  for (int it = 0; it < 16; ++it) {
    const int d4 = (tid & 15) + 16 * (it & 3);
    const int r  = (tid >> 4) + 16 * (it >> 2);
    const float4 xv = ((const float4*)(x + (rowBase + r) * DDIM))[d4];
    float4 o;
    o.x = xv.x - res[4 * d4 + 0][r];
    o.y = xv.y - res[4 * d4 + 1][r];
    o.z = xv.z - res[4 * d4 + 2][r];
    o.w = xv.w - res[4 * d4 + 3][r];
    ((float4*)(out + (rowBase + r) * DDIM))[d4] = o;
  }

  // ---- deterministic per-block loss partial ----
  float s = lossAcc;
  #pragma unroll
  for (int m = 32; m >= 1; m >>= 1) s += __shfl_xor(s, m);
  if ((tid & 63) == 0) red[tid >> 6] = s;
  __syncthreads();
  if (tid == 0) lossPart[blockIdx.x] = red[0] + red[1] + red[2] + red[3];
}

__global__ void loss_final(const float* __restrict__ part, float* __restrict__ outLoss) {
  __shared__ float buf[256];
  const int t = threadIdx.x;
  buf[t] = part[t] + part[t + 256] + part[t + 512] + part[t + 768];
  __syncthreads();
  for (int st = 128; st >= 1; st >>= 1) {
    if (t < st) buf[t] += buf[t + st];
    __syncthreads();
  }
  if (t == 0) *outLoss = buf[0] * (1.25f / 16777216.f);
}

extern "C" void kernel_launch(void* const* d_in, const int* in_sizes, int n_in,
                              void* d_out, int out_size, void* d_ws, size_t ws_size,
                              hipStream_t stream) {
  (void)in_sizes; (void)n_in; (void)out_size; (void)ws_size;
  const float* x   = (const float*)d_in[0];
  const float* emb = (const float*)d_in[1];
  float* out     = (float*)d_out;
  float* outLoss = out + (size_t)NROWS * DDIM;          // 16777216
  float* outIdx  = outLoss + 1;                         // indices as float
  float* e2      = (float*)d_ws;                        // 8192 floats
  float* part    = e2 + QSTAGES * KCODES;               // 1024 floats

  e2_kernel<<<dim3(QSTAGES * KCODES / 4), dim3(256), 0, stream>>>(emb, e2);
  rvq_kernel<<<dim3(NROWS / BR), dim3(256), 0, stream>>>(x, emb, e2, out, outIdx, part);
  loss_final<<<dim3(1), dim3(256), 0, stream>>>(part, outLoss);
}